// Round 6
// baseline (115.229 us; speedup 1.0000x reference)
//
#include <hip/hip_runtime.h>
#include <hip/hip_bf16.h>

#define SEQ 14
#define IN 24
#define H 64
#define CLS 10
#define NBATCH 65536

typedef __attribute__((ext_vector_type(4))) float f32x4;
typedef __attribute__((ext_vector_type(8))) short bf16x8;
typedef __attribute__((ext_vector_type(4))) short bf16x4;

#define MFMA(A, B, C) __builtin_amdgcn_mfma_f32_16x16x32_bf16(A, B, C, 0, 0, 0)
// Anti-rematerialization pin (R5-verified): keeps weight frags VGPR-resident.
#define PIN(v) asm volatile("" : "+v"(v))

static __device__ __forceinline__ short f2bf(float f) {
    __hip_bfloat16 h = __float2bfloat16(f);
    union { __hip_bfloat16 h; short s; } u; u.h = h;
    return u.s;
}
static __device__ __forceinline__ float fast_tanh(float v) {
    float e = __expf(2.0f * v);
    return 1.0f - 2.0f * __builtin_amdgcn_rcpf(e + 1.0f);
}
static __device__ __forceinline__ bf16x8 pack8(f32x4 a, f32x4 b) {
    bf16x8 r;
    r[0] = f2bf(a[0]); r[1] = f2bf(a[1]); r[2] = f2bf(a[2]); r[3] = f2bf(a[3]);
    r[4] = f2bf(b[0]); r[5] = f2bf(b[1]); r[6] = f2bf(b[2]); r[7] = f2bf(b[3]);
    return r;
}
static __device__ __forceinline__ bf16x8 loadw8(const float* p) {
    f32x4 v0 = *(const f32x4*)p;
    f32x4 v1 = *(const f32x4*)(p + 4);
    return pack8(v0, v1);
}

// Block = 64 threads = ONE wave owning 16 batch elems through all 3 layers.
// No __syncthreads anywhere: recurrent h and layer-to-layer h are produced and
// consumed by the same wave, via a wave-private LDS repack buffer.
// Lane fields: g = lane>>4, c = lane&15.
//   A-frag (weights): row-in-tile = c, k = 32f + 8g + j
//   B-frag (activations): batch col = c, k = 32f + 8g + j
//   D: batch col = c, row-in-tile = 4g + r
// L0 bias is baked into Wi0 column k=24 (x-frag carries 1.0 there).
__global__ __launch_bounds__(64, 2) void rnn_wave(
    const float* __restrict__ x,     // [B, T, 24]
    const float* __restrict__ h0in,  // [3, B, 64]
    const float* __restrict__ pWi0, const float* __restrict__ pWh0,
    const float* __restrict__ pbi0, const float* __restrict__ pbh0,
    const float* __restrict__ pWi1, const float* __restrict__ pWh1,
    const float* __restrict__ pbi1, const float* __restrict__ pbh1,
    const float* __restrict__ pWi2, const float* __restrict__ pWh2,
    const float* __restrict__ pbi2, const float* __restrict__ pbh2,
    const float* __restrict__ pWout, const float* __restrict__ pbout,
    float* __restrict__ out)         // [B*10] ++ [3*B*64]
{
    __shared__ __align__(16) short hlds[3][8][16][8];  // [layer][kg][c][e] bf16
    __shared__ float blds[2][H];                       // L1/L2 bias (f32)

    const int lane = threadIdx.x;    // block == wave
    const int g = lane >> 4;
    const int c = lane & 15;
    const int b0 = blockIdx.x * 16;

    // L1/L2 biases into LDS (same-wave produce/consume: no barrier).
    blds[0][lane] = pbi1[lane] + pbh1[lane];
    blds[1][lane] = pbi2[lane] + pbh2[lane];

    // ---- weight A-fragments, fully replicated per wave, pinned ----
    bf16x8 aWh[3][4][2];   // self (Wh0..2): 96 VGPR
    {
        const float* Whp[3] = { pWh0, pWh1, pWh2 };
#pragma unroll
        for (int l = 0; l < 3; ++l)
#pragma unroll
            for (int m = 0; m < 4; ++m)
#pragma unroll
                for (int f = 0; f < 2; ++f) {
                    aWh[l][m][f] = loadw8(Whp[l] + (16 * m + c) * H + f * 32 + g * 8);
                    PIN(aWh[l][m][f]);
                }
    }
    bf16x8 aWb[2][4][2];   // below (Wi1, Wi2): 64 VGPR
    {
        const float* Wip[2] = { pWi1, pWi2 };
#pragma unroll
        for (int l = 0; l < 2; ++l)
#pragma unroll
            for (int m = 0; m < 4; ++m)
#pragma unroll
                for (int f = 0; f < 2; ++f) {
                    aWb[l][m][f] = loadw8(Wip[l] + (16 * m + c) * H + f * 32 + g * 8);
                    PIN(aWb[l][m][f]);
                }
    }
    bf16x8 aWi0[4];        // 16 VGPR; g==3 lane carries L0 bias at k=24 (j=0)
#pragma unroll
    for (int m = 0; m < 4; ++m) {
        bf16x8 w;
        if (g < 3) {
            w = loadw8(pWi0 + (16 * m + c) * IN + g * 8);
        } else {
#pragma unroll
            for (int j = 0; j < 8; ++j) w[j] = 0;
            w[0] = f2bf(pbi0[16 * m + c] + pbh0[16 * m + c]);
        }
        aWi0[m] = w; PIN(aWi0[m]);
    }

    // ---- h state as B-fragments (bf16, registers) ----
    bf16x8 hB[3][2];
#pragma unroll
    for (int l = 0; l < 3; ++l)
#pragma unroll
        for (int f = 0; f < 2; ++f)
            hB[l][f] = loadw8(h0in + ((size_t)l * NBATCH + b0 + c) * H + f * 32 + g * 8);

    // constant x-frag for g==3 lanes: 1.0 at k=24 -> multiplies the baked bias
    bf16x8 xB3;
#pragma unroll
    for (int j = 0; j < 8; ++j) xB3[j] = 0;
    xB3[0] = (short)0x3F80;  // bf16 1.0

    float* hsout = out + (size_t)NBATCH * CLS;

#pragma unroll 1
    for (int t = 0; t < SEQ; ++t) {
        // ---------------- L0: below = x (global), self = hB[0] ----------------
        {
            bf16x8 xB = xB3;
            if (g < 3) {
                const float* xp = x + ((size_t)(b0 + c) * SEQ + t) * IN + g * 8;
                xB = pack8(*(const f32x4*)xp, *(const f32x4*)(xp + 4));
            }
#pragma unroll
            for (int m = 0; m < 4; ++m) {
                f32x4 acc = {0.f, 0.f, 0.f, 0.f};
                acc = MFMA(aWh[0][m][0], hB[0][0], acc);
                acc = MFMA(aWh[0][m][1], hB[0][1], acc);
                acc = MFMA(aWi0[m], xB, acc);     // includes bias via k=24
                f32x4 th;
#pragma unroll
                for (int r = 0; r < 4; ++r) th[r] = fast_tanh(acc[r]);
                if (t == SEQ - 1)
                    *(f32x4*)(hsout + (size_t)(b0 + c) * H + 16 * m + 4 * g) = th;
                bf16x4 pv;
#pragma unroll
                for (int r = 0; r < 4; ++r) pv[r] = f2bf(th[r]);
                *(bf16x4*)&hlds[0][2 * m + (g >> 1)][c][4 * (g & 1)] = pv;
            }
            hB[0][0] = *(const bf16x8*)&hlds[0][g][c][0];
            hB[0][1] = *(const bf16x8*)&hlds[0][4 + g][c][0];
        }
        // ---------------- L1 / L2 ----------------
#define LAYER12(li, bi_)                                                        \
        {                                                                       \
            _Pragma("unroll")                                                   \
            for (int m = 0; m < 4; ++m) {                                       \
                f32x4 acc = {0.f, 0.f, 0.f, 0.f};                               \
                acc = MFMA(aWh[li][m][0], hB[li][0], acc);                      \
                acc = MFMA(aWh[li][m][1], hB[li][1], acc);                      \
                acc = MFMA(aWb[li - 1][m][0], hB[li - 1][0], acc);              \
                acc = MFMA(aWb[li - 1][m][1], hB[li - 1][1], acc);              \
                f32x4 bv = *(const f32x4*)&blds[bi_][16 * m + 4 * g];           \
                f32x4 th;                                                       \
                _Pragma("unroll")                                               \
                for (int r = 0; r < 4; ++r) th[r] = fast_tanh(acc[r] + bv[r]);  \
                if (t == SEQ - 1)                                               \
                    *(f32x4*)(hsout + (size_t)(li) * NBATCH * H +               \
                              (size_t)(b0 + c) * H + 16 * m + 4 * g) = th;      \
                bf16x4 pv;                                                      \
                _Pragma("unroll")                                               \
                for (int r = 0; r < 4; ++r) pv[r] = f2bf(th[r]);                \
                *(bf16x4*)&hlds[li][2 * m + (g >> 1)][c][4 * (g & 1)] = pv;     \
            }                                                                   \
            hB[li][0] = *(const bf16x8*)&hlds[li][g][c][0];                     \
            hB[li][1] = *(const bf16x8*)&hlds[li][4 + g][c][0];                 \
        }
        LAYER12(1, 0)
        LAYER12(2, 1)
#undef LAYER12
    }

    // ---------------- logits head: MFMA with zero-padded 16-row Wout ----------
    {
        bf16x8 aWo[2];
#pragma unroll
        for (int f = 0; f < 2; ++f) {
            if (c < CLS) {
                aWo[f] = loadw8(pWout + c * H + f * 32 + g * 8);
            } else {
#pragma unroll
                for (int j = 0; j < 8; ++j) aWo[f][j] = 0;
            }
        }
        f32x4 acc = {0.f, 0.f, 0.f, 0.f};
        acc = MFMA(aWo[0], hB[2][0], acc);
        acc = MFMA(aWo[1], hB[2][1], acc);
        // D: batch col = c, cls = 4g + r
#pragma unroll
        for (int r = 0; r < 4; ++r) {
            int cls = 4 * g + r;
            if (cls < CLS)
                out[(size_t)(b0 + c) * CLS + cls] = acc[r] + pbout[cls];
        }
    }
}

extern "C" void kernel_launch(void* const* d_in, const int* in_sizes, int n_in,
                              void* d_out, int out_size, void* d_ws, size_t ws_size,
                              hipStream_t stream) {
    const float* x    = (const float*)d_in[0];
    const float* h0in = (const float*)d_in[1];
    const float* Wi0  = (const float*)d_in[2];
    const float* Wh0  = (const float*)d_in[3];
    const float* bi0  = (const float*)d_in[4];
    const float* bh0  = (const float*)d_in[5];
    const float* Wi1  = (const float*)d_in[6];
    const float* Wh1  = (const float*)d_in[7];
    const float* bi1  = (const float*)d_in[8];
    const float* bh1  = (const float*)d_in[9];
    const float* Wi2  = (const float*)d_in[10];
    const float* Wh2  = (const float*)d_in[11];
    const float* bi2  = (const float*)d_in[12];
    const float* bh2  = (const float*)d_in[13];
    const float* Wout = (const float*)d_in[14];
    const float* bout = (const float*)d_in[15];
    float* out = (float*)d_out;

    dim3 grid(NBATCH / 16), block(64);
    rnn_wave<<<grid, block, 0, stream>>>(x, h0in, Wi0, Wh0, bi0, bh0,
                                         Wi1, Wh1, bi1, bh1,
                                         Wi2, Wh2, bi2, bh2,
                                         Wout, bout, out);
}